// Round 5
// baseline (5118.864 us; speedup 1.0000x reference)
//
#include <hip/hip_runtime.h>
#include <hip/hip_cooperative_groups.h>
#include <math.h>

namespace cg = cooperative_groups;

#define NB 8
#define NN 2048
#define ND 128
#define NITER 32

// eps = blur^2 = (5e-5)^2 = 2.5e-9. All potentials stored in LOG2-scaled units:
// F2 = (f/eps)*log2e etc. M2_ij = dot_ij/eps*log2e = q_ij * S_tile(row).
#define EPS_F   2.5e-9f
#define LNEG2   (-11.0f)                                   /* log2(1/2048) */
#define HSCALE2 ((float)(0.5 * 1.4426950408889634 / 2.5e-9))
#define SK2     ((float)(1.4426950408889634 / (255.0 * 2.5e-9)))

// ---------- preprocessing ----------

// wx[d] = sum_t x[0,t,d]^2  (reference quirk: batch 0 only), same for y
__global__ __launch_bounds__(256) void k_colsum(const float* __restrict__ x,
                                                const float* __restrict__ y,
                                                float* __restrict__ wx,
                                                float* __restrict__ wy) {
    const float* in = blockIdx.y ? y : x;
    float* w = blockIdx.y ? wy : wx;
    int d = blockIdx.x;
    int t = threadIdx.x;
    float sum = 0.f;
    for (int k = t; k < NN; k += 256) {
        float v = in[(size_t)k * ND + d];
        sum += v * v;
    }
    for (int off = 32; off > 0; off >>= 1) sum += __shfl_down(sum, off);
    __shared__ float ls[4];
    if ((t & 63) == 0) ls[t >> 6] = sum;
    __syncthreads();
    if (t == 0) w[d] = ls[0] + ls[1] + ls[2] + ls[3];
}

// X2 = x^2 / wx; h2 = 0.5*|X2 row|^2/eps*log2e
__global__ __launch_bounds__(128) void k_norm(const float* __restrict__ x,
                                              const float* __restrict__ y,
                                              const float* __restrict__ wx,
                                              const float* __restrict__ wy,
                                              float* __restrict__ X2,
                                              float* __restrict__ Y2,
                                              float* __restrict__ hx,
                                              float* __restrict__ hy) {
    int gx = blockIdx.x;                 // b*NN + i
    const float* in = blockIdx.y ? y : x;
    const float* w  = blockIdx.y ? wy : wx;
    float* o  = blockIdx.y ? Y2 : X2;
    float* h  = blockIdx.y ? hy : hx;
    int d = threadIdx.x;
    size_t base = (size_t)gx * ND;
    float v = in[base + d];
    float v2 = (v * v) / w[d];
    o[base + d] = v2;
    float sq = v2 * v2;
    for (int off = 32; off > 0; off >>= 1) sq += __shfl_down(sq, off);
    __shared__ float ls[2];
    if ((d & 63) == 0) ls[d >> 6] = sq;
    __syncthreads();
    if (d == 0) h[gx] = (ls[0] + ls[1]) * HSCALE2;
}

__global__ __launch_bounds__(256) void k_init(const float* __restrict__ hx,
                                              const float* __restrict__ hy,
                                              float* __restrict__ Gt,
                                              float* __restrict__ Px, float* __restrict__ Pax,
                                              float* __restrict__ Py, float* __restrict__ Pay) {
    int tid = blockIdx.x * 256 + threadIdx.x;
    Gt[tid]  = LNEG2 - hy[tid];
    Px[tid]  = 0.f;
    Py[tid]  = 0.f;
    Pax[tid] = LNEG2 - hx[tid];
    Pay[tid] = LNEG2 - hy[tid];
}

__device__ __forceinline__ unsigned int pack4q(const float* a, float iv) {
    int q0 = (int)fmaf(a[0], iv, 0.5f); q0 = q0 > 255 ? 255 : q0;
    int q1 = (int)fmaf(a[1], iv, 0.5f); q1 = q1 > 255 ? 255 : q1;
    int q2 = (int)fmaf(a[2], iv, 0.5f); q2 = q2 > 255 ? 255 : q2;
    int q3 = (int)fmaf(a[3], iv, 0.5f); q3 = q3 > 255 ? 255 : q3;
    return (unsigned int)q0 | ((unsigned int)q1 << 8) | ((unsigned int)q2 << 16) | ((unsigned int)q3 << 24);
}

// ---------- GEMM + per-(row,128-col-tile) max quantization ----------
template<bool DO_T>
__global__ __launch_bounds__(256) void k_gemm(const float* __restrict__ A,
                                              const float* __restrict__ B,
                                              float* __restrict__ Srow,
                                              float* __restrict__ Scol,
                                              unsigned char* __restrict__ C,
                                              unsigned char* __restrict__ Ct,
                                              int b0) {
    __shared__ float As[32][132];
    __shared__ float Bs[32][132];
    __shared__ __align__(16) unsigned char T[128][144];
    __shared__ float sinv[128];
    int bi = blockIdx.x, bj = blockIdx.y, bz = blockIdx.z;
    size_t bg = (size_t)(b0 + bz);
    const float* Ab = A + (bg * NN + (size_t)bi * 128) * ND;
    const float* Bb = B + (bg * NN + (size_t)bj * 128) * ND;
    int t = threadIdx.x;
    int tx = t & 15, ty = t >> 4;
    float acc[8][8];
#pragma unroll
    for (int i = 0; i < 8; ++i)
#pragma unroll
        for (int j = 0; j < 8; ++j) acc[i][j] = 0.f;
    int lr = t >> 3;            // 0..31
    int kq = (t & 7) << 2;      // k-quad
    for (int kt = 0; kt < ND; kt += 32) {
        __syncthreads();
#pragma unroll
        for (int s2 = 0; s2 < 4; ++s2) {
            int r = lr + (s2 << 5);
            float4 av = *(const float4*)(Ab + (size_t)r * ND + kt + kq);
            As[kq + 0][r] = av.x; As[kq + 1][r] = av.y; As[kq + 2][r] = av.z; As[kq + 3][r] = av.w;
            float4 bv = *(const float4*)(Bb + (size_t)r * ND + kt + kq);
            Bs[kq + 0][r] = bv.x; Bs[kq + 1][r] = bv.y; Bs[kq + 2][r] = bv.z; Bs[kq + 3][r] = bv.w;
        }
        __syncthreads();
#pragma unroll
        for (int k = 0; k < 32; ++k) {
            float a[8], bb[8];
            *(float4*)(a + 0)  = *(const float4*)&As[k][4 * ty];
            *(float4*)(a + 4)  = *(const float4*)&As[k][64 + 4 * ty];
            *(float4*)(bb + 0) = *(const float4*)&Bs[k][4 * tx];
            *(float4*)(bb + 4) = *(const float4*)&Bs[k][64 + 4 * tx];
#pragma unroll
            for (int i = 0; i < 8; ++i)
#pragma unroll
                for (int j = 0; j < 8; ++j)
                    acc[i][j] = fmaf(a[i], bb[j], acc[i][j]);
        }
    }
    // ---- row-tile maxes (shuffle across the 16 tx lanes) + pack pass 1 ----
    float inv_r[8];
#pragma unroll
    for (int i = 0; i < 8; ++i) {
        float m0 = fmaxf(fmaxf(fmaxf(acc[i][0], acc[i][1]), fmaxf(acc[i][2], acc[i][3])),
                         fmaxf(fmaxf(acc[i][4], acc[i][5]), fmaxf(acc[i][6], acc[i][7])));
#pragma unroll
        for (int off = 1; off <= 8; off <<= 1) m0 = fmaxf(m0, __shfl_xor(m0, off));
        m0 = fmaxf(m0, 1e-30f);
        inv_r[i] = 255.f / m0;
        if (tx == 0) {
            int m = ((i & 4) << 4) + 4 * ty + (i & 3);
            Srow[(bg * NN + (size_t)bi * 128 + m) * 16 + bj] = m0 * SK2;
        }
    }
    __syncthreads();
#pragma unroll
    for (int i = 0; i < 8; ++i) {
        int m = ((i & 4) << 4) + 4 * ty + (i & 3);
        *(unsigned int*)&T[m][4 * tx]      = pack4q(&acc[i][0], inv_r[i]);
        *(unsigned int*)&T[m][64 + 4 * tx] = pack4q(&acc[i][4], inv_r[i]);
    }
    __syncthreads();
    {
        int r = t >> 1, hf = t & 1;
        size_t grow = (size_t)bz * NN + (size_t)bi * 128 + r;
        unsigned char* dst = C + grow * NN + (size_t)bj * 128 + 64 * hf;
        const uint4* src = (const uint4*)&T[r][64 * hf];
        uint4 v0 = src[0], v1 = src[1], v2 = src[2], v3 = src[3];
        *(uint4*)(dst + 0)  = v0;
        *(uint4*)(dst + 16) = v1;
        *(uint4*)(dst + 32) = v2;
        *(uint4*)(dst + 48) = v3;
    }
    if (DO_T) {
        __syncthreads();                    // T stores consumed; reuse as col-max buffer
        float* CMf = (float*)&T[0][0];      // 16 x 128 floats (8 KB) aliasing T
#pragma unroll
        for (int j = 0; j < 8; ++j) {
            float cm = acc[0][j];
#pragma unroll
            for (int i = 1; i < 8; ++i) cm = fmaxf(cm, acc[i][j]);
            int jl = (j < 4) ? (4 * tx + j) : (60 + 4 * tx + j);
            CMf[ty * 128 + jl] = cm;
        }
        __syncthreads();
        if (t < 128) {
            float cm = CMf[t];
#pragma unroll
            for (int k = 1; k < 16; ++k) cm = fmaxf(cm, CMf[k * 128 + t]);
            cm = fmaxf(cm, 1e-30f);
            Scol[(bg * NN + (size_t)bj * 128 + t) * 16 + bi] = cm * SK2;
            sinv[t] = 255.f / cm;
        }
        __syncthreads();
#pragma unroll
        for (int i = 0; i < 8; ++i) {
            int m = ((i & 4) << 4) + 4 * ty + (i & 3);
#pragma unroll
            for (int j = 0; j < 8; ++j) {
                int jl = (j < 4) ? (4 * tx + j) : (60 + 4 * tx + j);
                int q = (int)fmaf(acc[i][j], sinv[jl], 0.5f);
                T[jl][m] = (unsigned char)(q > 255 ? 255 : q);
            }
        }
        __syncthreads();
        {
            int r = t >> 1, hf = t & 1;
            size_t grow = (size_t)bz * NN + (size_t)bj * 128 + r;
            unsigned char* dst = Ct + grow * NN + (size_t)bi * 128 + 64 * hf;
            const uint4* src = (const uint4*)&T[r][64 * hf];
            uint4 v0 = src[0], v1 = src[1], v2 = src[2], v3 = src[3];
            *(uint4*)(dst + 0)  = v0;
            *(uint4*)(dst + 16) = v1;
            *(uint4*)(dst + 32) = v2;
            *(uint4*)(dst + 48) = v3;
        }
    }
}

// ---------- Sinkhorn iteration phase (shared by coop + fallback kernels) ----------
struct SArgs {
    const unsigned char *Qxy, *Qyx, *Qxx, *Qyy;   // group-relative [G][2048][2048]
    const float *Sxy, *Syx, *Sxx, *Syy;           // global [NB*NN*16]
    float *Fa, *Gt, *Px, *Py;                     // global [NB*NN]
    float *PaxA, *PaxB, *PayA, *PayB;             // global [NB*NN]
    const float *hx, *hy;                         // global [NB*NN]
    int b0;                                       // batch base of this group
};

// Grid decode: nblk = 64*G blocks. Half 0: lse pass (f or g). Half 1: sym pass.
// Per half: 32 blocks/batch, 64 rows/block, 16 rows/wave.
__device__ __forceinline__ void sink_phase(const SArgs& a, int bid, int nblk,
                                           int cur, int ph, float* vs) {
    int half = nblk >> 1;
    int mh = bid >= half;
    int rem = mh ? bid - half : bid;
    int brel = rem >> 5;
    int r0 = (rem & 31) << 6;
    int t = threadIdx.x;
    int w = t >> 6, l = t & 63;
    size_t bg = (size_t)(a.b0 + brel);
    size_t gx0 = (bg << 11) + r0 + (w << 4);                       // global row base (this wave)
    size_t qbase = ((((size_t)brel << 11) + r0 + (w << 4)) << 11); // group-relative Q offset

    const unsigned char* Q;
    const float* S;
    const float* v;
    float* Pa_w = nullptr;
    const float* hp = nullptr;
    float* Pp = nullptr;
    if (ph == 0) {
        if (mh == 0) { Q = a.Qxy; S = a.Sxy; v = a.Gt + (bg << 11); }
        else { Q = a.Qxx; S = a.Sxx; v = (cur ? a.PaxB : a.PaxA) + (bg << 11);
               Pa_w = cur ? a.PaxA : a.PaxB; hp = a.hx; Pp = a.Px; }
    } else {
        if (mh == 0) { Q = a.Qyx; S = a.Syx; v = a.Fa + (bg << 11); }
        else { Q = a.Qyy; S = a.Syy; v = (cur ? a.PayB : a.PayA) + (bg << 11);
               Pa_w = cur ? a.PayA : a.PayB; hp = a.hy; Pp = a.Py; }
    }
    float* out0 = (ph == 0) ? a.Fa : a.Gt;

    // stage v into LDS with XOR swizzle (breaks 128B-stride bank conflict)
    {
        const float4* gv = (const float4*)v;
        float4 a0 = gv[2 * t], a1 = gv[2 * t + 1];
        int B0 = t << 5;
        int sw = ((t >> 2) & 7) << 4;
        *(float4*)((char*)vs + (B0 ^ sw)) = a0;
        *(float4*)((char*)vs + ((B0 + 16) ^ sw)) = a1;
    }
    __syncthreads();
    float vv[32];
#pragma unroll
    for (int u = 0; u < 8; ++u) {
        int B = ((l << 7) + (u << 4)) ^ ((l & 7) << 4);
        *(float4*)&vv[u * 4] = *(const float4*)((char*)vs + B);
    }

    const unsigned char* rp0 = Q + qbase + ((size_t)l << 5);
    uint4 qa = *(const uint4*)rp0;
    uint4 qb = *(const uint4*)(rp0 + 16);
    float sc = S[(gx0 << 4) + (l >> 2)];
#pragma unroll 1
    for (int r = 0; r < 16; ++r) {
        uint4 na, nb2; float nsc;
        if (r < 15) {
            const unsigned char* np = rp0 + ((size_t)(r + 1) << 11);
            na = *(const uint4*)np;
            nb2 = *(const uint4*)(np + 16);
            nsc = S[((gx0 + r + 1) << 4) + (l >> 2)];
        }
        unsigned int qs[8] = {qa.x, qa.y, qa.z, qa.w, qb.x, qb.y, qb.z, qb.w};
        float m0 = -INFINITY, m1 = -INFINITY, m2 = -INFINITY, m3 = -INFINITY;
#pragma unroll
        for (int u = 0; u < 8; ++u) {
            unsigned int q = qs[u];
            m0 = fmaxf(m0, fmaf((float)(unsigned char)(q      ), sc, vv[4 * u + 0]));
            m1 = fmaxf(m1, fmaf((float)(unsigned char)(q >>  8), sc, vv[4 * u + 1]));
            m2 = fmaxf(m2, fmaf((float)(unsigned char)(q >> 16), sc, vv[4 * u + 2]));
            m3 = fmaxf(m3, fmaf((float)(q >> 24),                sc, vv[4 * u + 3]));
        }
        float mx = fmaxf(fmaxf(m0, m1), fmaxf(m2, m3));
#pragma unroll
        for (int off = 32; off; off >>= 1) mx = fmaxf(mx, __shfl_xor(mx, off));
        float s0 = 0.f, s1 = 0.f, s2 = 0.f, s3 = 0.f;
#pragma unroll
        for (int u = 0; u < 8; ++u) {
            unsigned int q = qs[u];
            s0 += exp2f(fmaf((float)(unsigned char)(q      ), sc, vv[4 * u + 0]) - mx);
            s1 += exp2f(fmaf((float)(unsigned char)(q >>  8), sc, vv[4 * u + 1]) - mx);
            s2 += exp2f(fmaf((float)(unsigned char)(q >> 16), sc, vv[4 * u + 2]) - mx);
            s3 += exp2f(fmaf((float)(q >> 24),                sc, vv[4 * u + 3]) - mx);
        }
        float ss = (s0 + s1) + (s2 + s3);
#pragma unroll
        for (int off = 32; off; off >>= 1) ss += __shfl_xor(ss, off);
        if (l == 0) {
            size_t gx = gx0 + r;
            float lse2 = mx + log2f(ss);
            if (mh == 0) {
                out0[gx] = LNEG2 - lse2;
            } else {
                float pn = 0.5f * (Pp[gx] + hp[gx] - lse2);
                Pp[gx] = pn;
                Pa_w[gx] = LNEG2 + pn - hp[gx];
            }
        }
        qa = na; qb = nb2; sc = nsc;
    }
}

__global__ __launch_bounds__(256, 2) void k_sink(SArgs a) {
    cg::grid_group grid = cg::this_grid();
    __shared__ __align__(16) float vs[2048];
    int cur = 0;
    for (int it = 0; it < NITER; ++it) {
        sink_phase(a, blockIdx.x, gridDim.x, cur, 0, vs);
        grid.sync();
        sink_phase(a, blockIdx.x, gridDim.x, cur, 1, vs);
        grid.sync();
        cur ^= 1;
    }
}

// Fallback: one phase per launch (inter-launch sync replaces grid.sync)
__global__ __launch_bounds__(256, 2) void k_step(SArgs a, int cur, int ph) {
    __shared__ __align__(16) float vs[2048];
    sink_phase(a, blockIdx.x, gridDim.x, cur, ph, vs);
}

// ---------- final reduction (log2 domain -> natural) ----------
__global__ __launch_bounds__(256) void k_final(const float* __restrict__ Fa, const float* __restrict__ Gt,
                                               const float* __restrict__ Px, const float* __restrict__ Py,
                                               const float* __restrict__ hx, const float* __restrict__ hy,
                                               float* __restrict__ out) {
    int t = threadIdx.x;
    double acc = 0.0;
    for (int i = t; i < NB * NN; i += 256) {
        acc += (double)(Fa[i] + hx[i]) + (double)(Gt[i] + hy[i])
             - (double)Px[i] - (double)Py[i];
    }
    __shared__ double ld[256];
    ld[t] = acc;
    __syncthreads();
    for (int off = 128; off > 0; off >>= 1) {
        if (t < off) ld[t] += ld[t + off];
        __syncthreads();
    }
    if (t == 0) {
        double total = ld[0] - 2.0 * (double)LNEG2 * (double)(NB * NN);
        out[0] = (float)((double)EPS_F * 0.6931471805599453 * total / (double)NN);
    }
}

extern "C" void kernel_launch(void* const* d_in, const int* in_sizes, int n_in,
                              void* d_out, int out_size, void* d_ws, size_t ws_size,
                              hipStream_t stream) {
    (void)in_sizes; (void)n_in; (void)out_size;
    const float* x = (const float*)d_in[0];
    const float* y = (const float*)d_in[1];
    float* out = (float*)d_out;

    char* ws = (char*)d_ws;
    size_t off = 0;
    auto alloc = [&](size_t bytes) -> char* {
        char* p = ws + off;
        off += (bytes + 255) & ~(size_t)255;
        return p;
    };

    float* X2 = (float*)alloc((size_t)NB * NN * ND * 4);
    float* Y2 = (float*)alloc((size_t)NB * NN * ND * 4);
    float* wx = (float*)alloc(ND * 4);
    float* wy = (float*)alloc(ND * 4);
    float* hx = (float*)alloc((size_t)NB * NN * 4);
    float* hy = (float*)alloc((size_t)NB * NN * 4);
    float* Fa = (float*)alloc((size_t)NB * NN * 4);
    float* Gt = (float*)alloc((size_t)NB * NN * 4);
    float* Px = (float*)alloc((size_t)NB * NN * 4);
    float* Py = (float*)alloc((size_t)NB * NN * 4);
    float* PaxA = (float*)alloc((size_t)NB * NN * 4);
    float* PaxB = (float*)alloc((size_t)NB * NN * 4);
    float* PayA = (float*)alloc((size_t)NB * NN * 4);
    float* PayB = (float*)alloc((size_t)NB * NN * 4);
    float* Sxy = (float*)alloc((size_t)NB * NN * 16 * 4);
    float* Syx = (float*)alloc((size_t)NB * NN * 16 * 4);
    float* Sxx = (float*)alloc((size_t)NB * NN * 16 * 4);
    float* Syy = (float*)alloc((size_t)NB * NN * 16 * 4);

    // Q matrices: 4 * 4MB per batch in group; shrink group if workspace is small
    size_t small_end = off;
    size_t matBytes = (size_t)NN * NN;               // 4 MB (u8)
    int G = NB;
    while (G > 1 && small_end + 4 * matBytes * (size_t)G + 4096 > ws_size) G >>= 1;
    unsigned char* Qxy = (unsigned char*)alloc(matBytes * (size_t)G);
    unsigned char* Qyx = (unsigned char*)alloc(matBytes * (size_t)G);
    unsigned char* Qxx = (unsigned char*)alloc(matBytes * (size_t)G);
    unsigned char* Qyy = (unsigned char*)alloc(matBytes * (size_t)G);

    k_colsum<<<dim3(ND, 2), 256, 0, stream>>>(x, y, wx, wy);
    k_norm<<<dim3(NB * NN, 2), 128, 0, stream>>>(x, y, wx, wy, X2, Y2, hx, hy);
    k_init<<<dim3(NB * NN / 256), 256, 0, stream>>>(hx, hy, Gt, Px, PaxA, Py, PayA);

    for (int b0 = 0; b0 < NB; b0 += G) {
        k_gemm<true><<<dim3(16, 16, G), 256, 0, stream>>>(X2, Y2, Sxy, Syx, Qxy, Qyx, b0);
        k_gemm<false><<<dim3(16, 16, G), 256, 0, stream>>>(X2, X2, Sxx, nullptr, Qxx, nullptr, b0);
        k_gemm<false><<<dim3(16, 16, G), 256, 0, stream>>>(Y2, Y2, Syy, nullptr, Qyy, nullptr, b0);

        SArgs sa;
        sa.Qxy = Qxy; sa.Qyx = Qyx; sa.Qxx = Qxx; sa.Qyy = Qyy;
        sa.Sxy = Sxy; sa.Syx = Syx; sa.Sxx = Sxx; sa.Syy = Syy;
        sa.Fa = Fa; sa.Gt = Gt; sa.Px = Px; sa.Py = Py;
        sa.PaxA = PaxA; sa.PaxB = PaxB; sa.PayA = PayA; sa.PayB = PayB;
        sa.hx = hx; sa.hy = hy; sa.b0 = b0;
        void* kargs[] = { &sa };
        int nblk = 64 * G;
        hipError_t e = hipLaunchCooperativeKernel((void*)k_sink, dim3(nblk), dim3(256),
                                                  kargs, 0, stream);
        if (e != hipSuccess) {
            // fallback: per-phase launches (inter-launch sync replaces grid.sync)
            (void)hipGetLastError();   // clear the error state
            int cur = 0;
            for (int it = 0; it < NITER; ++it) {
                k_step<<<dim3(nblk), 256, 0, stream>>>(sa, cur, 0);
                k_step<<<dim3(nblk), 256, 0, stream>>>(sa, cur, 1);
                cur ^= 1;
            }
        }
    }
    k_final<<<dim3(1), 256, 0, stream>>>(Fa, Gt, Px, Py, hx, hy, out);
}